// Round 7
// baseline (512.908 us; speedup 1.0000x reference)
//
#include <hip/hip_runtime.h>
#include <cstdint>
#include <cstddef>

#define A_TOTAL 261888
#define NBATCH  16
#define KTOP    1000
#define CAP     2048
#define NMS_T   0.7f
#define F4_PER_IMG 65472          // 261888/4
#define F4_PER_BLK 1023           // 65472/64 blocks
#define STAGE_CAP 512             // per-block candidate staging (expected ~19)

// ---- ws layout (bytes) ----
#define WS_HP    0                 // 16*64*256*4 = 1,048,576  coarse hist partials
#define WS_CNT   1048576           // 16 ints (atomic accumulator -> zeroed in k_init)
#define WS_B0C   1048640           // 16 ints (threshold bin, written by k_scan)
#define WS_CAND  1048704           // 16*2048*8   = 262,144
#define WS_IOUA  1310848           // 16*1000*16  = 256,000
#define WS_POUT  1566848           // 256,000
#define WS_SOUT  1822848           // 64,000
#define WS_AOUT  1886848           // 64,000 ; end = 1,950,848

__constant__ float c_stride[5] = {4.f, 8.f, 16.f, 32.f, 64.f};
__constant__ float c_aw[5][3] = {
  {(float)(32.0 /0.707106769084930419921875),  32.f, (float)(32.0 /1.41421353816986083984375)},
  {(float)(64.0 /0.707106769084930419921875),  64.f, (float)(64.0 /1.41421353816986083984375)},
  {(float)(128.0/0.707106769084930419921875), 128.f, (float)(128.0/1.41421353816986083984375)},
  {(float)(256.0/0.707106769084930419921875), 256.f, (float)(256.0/1.41421353816986083984375)},
  {(float)(512.0/0.707106769084930419921875), 512.f, (float)(512.0/1.41421353816986083984375)}};
__constant__ float c_ah[5][3] = {
  {(float)(32.0 *0.707106769084930419921875),  32.f, (float)(32.0 *1.41421353816986083984375)},
  {(float)(64.0 *0.707106769084930419921875),  64.f, (float)(64.0 *1.41421353816986083984375)},
  {(float)(128.0*0.707106769084930419921875), 128.f, (float)(128.0*1.41421353816986083984375)},
  {(float)(256.0*0.707106769084930419921875), 256.f, (float)(256.0*1.41421353816986083984375)},
  {(float)(512.0*0.707106769084930419921875), 512.f, (float)(512.0*1.41421353816986083984375)}};

__device__ __forceinline__ void decompA(int a, int& l, int& i) {
  if (a < 245760) {
    if (a < 196608) { l = 0; i = a; } else { l = 1; i = a - 196608; }
  } else if (a < 258048) { l = 2; i = a - 245760; }
  else if (a < 261120)   { l = 3; i = a - 258048; }
  else                   { l = 4; i = a - 261120; }
}

__device__ __forceinline__ void decompE(int e, int& l, int& el) {
  if (e < 245760) {
    if (e < 196608) { l = 0; el = e; } else { l = 1; el = e - 196608; }
  } else if (e < 258048) { l = 2; el = e - 245760; }
  else if (e < 261120)   { l = 3; el = e - 258048; }
  else                   { l = 4; el = e - 261120; }
}

__device__ __forceinline__ int bin_of(float s) {
  int b = (int)(s * 16384.0f);
  return b > 16383 ? 16383 : (b < 0 ? 0 : b);
}

__device__ __forceinline__ float4 score4_at(const float* c0, const float* c1,
                                            const float* c2, const float* c3,
                                            const float* c4, int b, int f) {
  int l, off4;
  if (f < 49152) { l = 0; off4 = f; }
  else if (f < 61440) { l = 1; off4 = f - 49152; }
  else if (f < 64512) { l = 2; off4 = f - 61440; }
  else if (f < 65280) { l = 3; off4 = f - 64512; }
  else { l = 4; off4 = f - 65280; }
  int HW4x3 = 3 * (16384 >> (2 * l));
  const float4* p = (const float4*)((l == 0) ? c0 : (l == 1) ? c1 : (l == 2) ? c2
                                     : (l == 3) ? c3 : c4);
  float4 x = p[(size_t)b * HW4x3 + off4];
  float4 s;
  s.x = 1.0f / (1.0f + expf(-x.x));
  s.y = 1.0f / (1.0f + expf(-x.y));
  s.z = 1.0f / (1.0f + expf(-x.z));
  s.w = 1.0f / (1.0f + expf(-x.w));
  return s;
}

__device__ __forceinline__ void decode_box(const float* b0p, const float* b1p,
                                           const float* b2p, const float* b3p,
                                           const float* b4p, int b, int a,
                                           float& x1, float& y1, float& x2, float& y2,
                                           float& cx, float& cy, float& wb, float& hb) {
  int l, i; decompA(a, l, i);
  unsigned pix = (unsigned)i / 3u;
  int r = i - (int)pix * 3;
  int W = 256 >> l;
  int HW = 65536 >> (2 * l);
  int hh_i = (int)pix >> (8 - l);
  int ww_i = (int)pix & (W - 1);
  const float* bp = (l == 0) ? b0p : (l == 1) ? b1p : (l == 2) ? b2p : (l == 3) ? b3p : b4p;
  size_t base = (size_t)(b * 12 + r * 4) * HW + (size_t)pix;
  float d0 = bp[base];
  float d1 = bp[base + HW];
  float d2 = bp[base + 2 * (size_t)HW];
  float d3 = bp[base + 3 * (size_t)HW];
  float stride = c_stride[l];
  float cxa = ((float)ww_i + 0.5f) * stride;
  float cya = ((float)hh_i + 0.5f) * stride;
  float aw = c_aw[l][r], ah = c_ah[l][r];
  cx = cxa + d0 * aw;
  cy = cya + d1 * ah;
  wb = aw * expf(fminf(fmaxf(d2, -4.f), 4.f));
  hb = ah * expf(fminf(fmaxf(d3, -4.f), 4.f));
  x1 = cx - wb * 0.5f; x2 = cx + wb * 0.5f;
  y1 = cy - hb * 0.5f; y2 = cy + hb * 0.5f;
}

// ---------------- K1: zero output + cnt  AND  coarse histogram partials ----------------
__global__ __launch_bounds__(256) void k_init(const float* c0, const float* c1,
                                              const float* c2, const float* c3,
                                              const float* c4,
                                              float4* o, int n4, int* cnt, int* hp) {
  __shared__ int lh[256];
  int bx = blockIdx.x, tid = threadIdx.x;
  int gstride = gridDim.x * 256;
  float4 z = make_float4(0.f, 0.f, 0.f, 0.f);
  for (int i = bx * 256 + tid; i < n4; i += gstride) o[i] = z;
  if (bx == 0 && tid < NBATCH) cnt[tid] = 0;
  if (bx < 1024) {
    lh[tid] = 0;
    __syncthreads();
    int b = bx >> 6, blk = bx & 63;
    int f0 = blk * F4_PER_BLK;
    #pragma unroll
    for (int it = 0; it < 4; it++) {
      int f = f0 + it * 256 + tid;
      if (f < f0 + F4_PER_BLK) {
        float4 s = score4_at(c0, c1, c2, c3, c4, b, f);
        atomicAdd(&lh[bin_of(s.x) >> 6], 1);
        atomicAdd(&lh[bin_of(s.y) >> 6], 1);
        atomicAdd(&lh[bin_of(s.z) >> 6], 1);
        atomicAdd(&lh[bin_of(s.w) >> 6], 1);
      }
    }
    __syncthreads();
    hp[(size_t)(b * 64 + blk) * 256 + tid] = lh[tid];
  }
}

// ---------------- K2: one-shot threshold scan (16 blocks) ----------------
__global__ __launch_bounds__(256) void k_scan(const int* hp, int* b0c) {
  __shared__ int ch[256];
  int b = blockIdx.x, t = threadIdx.x;
  int s = 0;
  for (int k = 0; k < 64; k++) s += hp[(size_t)(b * 64 + k) * 256 + t];
  ch[t] = s;
  __syncthreads();
  if (t == 0) {
    int acc = 0, cs = 0;
    for (int cb = 255; cb >= 0; cb--) {
      if (acc + ch[cb] >= KTOP) { cs = cb; break; }
      acc += ch[cb];
    }
    b0c[b] = cs * 64;   // superset threshold; exact top-K recovered by ranking
  }
}

// ---------------- K3: compact superset candidates ----------------
__global__ __launch_bounds__(256) void k_compact(const float* c0, const float* c1,
                                                 const float* c2, const float* c3,
                                                 const float* c4, const int* b0c,
                                                 int* cnt, unsigned long long* cand) {
  __shared__ unsigned long long stage[STAGE_CAP];
  __shared__ int lc, gbase;
  int b = blockIdx.y, blk = blockIdx.x, tid = threadIdx.x;
  if (tid == 0) lc = 0;
  __syncthreads();
  int B0v = b0c[b];
  int f0 = blk * F4_PER_BLK;
  #pragma unroll
  for (int it = 0; it < 4; it++) {
    int f = f0 + it * 256 + tid;
    if (f < f0 + F4_PER_BLK) {
      float4 sc4 = score4_at(c0, c1, c2, c3, c4, b, f);
      float sv[4] = {sc4.x, sc4.y, sc4.z, sc4.w};
      #pragma unroll
      for (int j = 0; j < 4; j++) {
        if (bin_of(sv[j]) >= B0v) {
          int e = f * 4 + j;
          int l, el; decompE(e, l, el);
          int shift = 16 - 2 * l;
          int r = el >> shift;
          int pix = el & ((1 << shift) - 1);
          int a = (e - el) + pix * 3 + r;
          int pos = atomicAdd(&lc, 1);
          if (pos < STAGE_CAP) {
            unsigned key = ~__float_as_uint(sv[j]);
            stage[pos] = ((unsigned long long)key << 32) | (unsigned)a;
          }
        }
      }
    }
  }
  __syncthreads();
  if (tid == 0) {
    int c = lc; if (c > STAGE_CAP) c = STAGE_CAP;
    lc = c;
    gbase = atomicAdd(&cnt[b], c);
  }
  __syncthreads();
  int c = lc, g0 = gbase;
  for (int t = tid; t < c; t += 256) {
    int gp = g0 + t;
    if (gp < CAP) cand[(size_t)b * CAP + gp] = stage[t];
  }
}

// ---------------- K4: exact rank-by-count + decode (1 wave/block, 128 slots) ----------------
__global__ __launch_bounds__(64) void k_rank(const float* b0p, const float* b1p,
                                             const float* b2p, const float* b3p,
                                             const float* b4p,
                                             const unsigned long long* cand,
                                             const int* cnt,
                                             float4* iouA, float4* pout,
                                             float* sout, int* aout) {
  __shared__ unsigned long long sk[CAP];
  int b = blockIdx.y, g = blockIdx.x;
  int lane = threadIdx.x;
  int n = cnt[b]; if (n > CAP) n = CAP;
  for (int t = lane; t < CAP; t += 64)
    sk[t] = (t < n) ? cand[(size_t)b * CAP + t] : ~0ull;
  __syncthreads();
  int s0 = g * 128 + lane, s1 = s0 + 64;
  unsigned long long my0 = sk[s0], my1 = sk[s1];
  int r0 = 0, r1 = 0;
  #pragma unroll 4
  for (int j = 0; j < n; j++) {
    unsigned long long k = sk[j];
    r0 += (k < my0) ? 1 : 0;
    r1 += (k < my1) ? 1 : 0;
  }
  #pragma unroll
  for (int pass = 0; pass < 2; pass++) {
    int slot = pass == 0 ? s0 : s1;
    int r = pass == 0 ? r0 : r1;
    unsigned long long e = pass == 0 ? my0 : my1;
    if (slot < n && r < KTOP) {
      int a = (int)(unsigned)e;
      float sc = __uint_as_float(~(unsigned)(e >> 32));
      float x1, y1, x2, y2, cx, cy, wb, hb;
      decode_box(b0p, b1p, b2p, b3p, b4p, b, a, x1, y1, x2, y2, cx, cy, wb, hb);
      int o = b * KTOP + r;
      iouA[o] = make_float4(x1, y1, x2, y2);
      pout[o] = make_float4(cx, cy, wb, hb);
      sout[o] = sc;
      aout[o] = a;
    }
  }
}

// ---------------- K5: fused lazy NMS (diag + ballot greedy + lazy suppression) ----------------
__global__ __launch_bounds__(1024) void k_nms(const float4* iouA, const float4* pout,
                                              const float* sout, const int* aout,
                                              float* out5, float* keepo) {
  __shared__ float4 bx[KTOP];                 // 16 KB boxes (x1,y1,x2,y2)
  __shared__ unsigned long long diag[1024];   // 8 KB chunk-local words
  __shared__ unsigned long long rem[16];      // suppressed-column words
  __shared__ unsigned long long kept64v[16];  // kept words per chunk
  int b = blockIdx.x;
  int tid = threadIdx.x;
  int wv = tid >> 6, lane = tid & 63;
  if (tid < KTOP) bx[tid] = iouA[b * KTOP + tid];
  if (tid < 16) { rem[tid] = 0ull; kept64v[tid] = 0ull; }
  __syncthreads();

  // wave wv owns column mycol = wv*64+lane (box in registers -> conflict-free)
  int mycol = wv * 64 + lane;
  bool colok = mycol < KTOP;
  float4 cb = colok ? bx[mycol] : make_float4(0.f, 0.f, 0.f, 0.f);
  float car = (cb.z - cb.x) * (cb.w - cb.y);

  // diag precompute: wave wv handles chunk wv (rows wv*64+i vs cols wv*64+lane)
  {
    int rbase = wv * 64;
    for (int i = 0; i < 64; i++) {
      int row = rbase + i;
      bool bit = false;
      if (row < KTOP && colok && mycol != row) {
        float4 rb = bx[row];
        float rar = (rb.z - rb.x) * (rb.w - rb.y);
        float iw = fminf(rb.z, cb.z) - fmaxf(rb.x, cb.x); iw = fmaxf(iw, 0.f);
        float ih = fminf(rb.w, cb.w) - fmaxf(rb.y, cb.y); ih = fmaxf(ih, 0.f);
        float inter = iw * ih;
        float iou = inter / (rar + car - inter + 1e-6f);
        bit = iou > NMS_T;
      }
      unsigned long long wbits = __ballot(bit);
      if (lane == 0) diag[row] = wbits;
    }
  }
  __syncthreads();

  for (int c = 0; c < 16; c++) {
    // phase A: wave 0 greedy-resolves chunk c (LDS only)
    if (wv == 0) {
      int row = c * 64 + lane;
      unsigned long long w = diag[c * 64 + lane];
      unsigned long long remc = rem[c];
      int sup = (row < KTOP) ? (int)((remc >> lane) & 1ull) : 1;
      for (int i = 0; i < 64; i++) {
        unsigned long long bal = __ballot(sup == 0);
        if (lane > i && ((bal >> i) & 1ull) && ((w >> i) & 1ull)) sup = 1;
      }
      unsigned long long km = __ballot(sup == 0);
      if (lane == 0) kept64v[c] = km;
    }
    __syncthreads();
    // phase B: lazy suppression — wave wv updates rem[wv] over kept rows of chunk c
    if (c < 15) {
      unsigned long long m = kept64v[c];
      bool hit = false;
      while (m) {
        int r = __ffsll((unsigned long long)m) - 1;
        m &= m - 1;
        int row = c * 64 + r;
        float4 rb = bx[row];                     // broadcast LDS read (free)
        float rar = (rb.z - rb.x) * (rb.w - rb.y);
        float iw = fminf(rb.z, cb.z) - fmaxf(rb.x, cb.x); iw = fmaxf(iw, 0.f);
        float ih = fminf(rb.w, cb.w) - fmaxf(rb.y, cb.y); ih = fmaxf(ih, 0.f);
        float inter = iw * ih;
        float iou = inter / (rar + car - inter + 1e-6f);
        if (colok && mycol != row && iou > NMS_T) hit = true;
      }
      unsigned long long wbits = __ballot(hit);
      if (lane == 0) rem[wv] |= wbits;
    }
    __syncthreads();
  }

  // scatter write
  if (tid < KTOP && ((kept64v[tid >> 6] >> (tid & 63)) & 1ull)) {
    int o = b * KTOP + tid;
    float4 pq = pout[o];
    float sc = sout[o];
    int a = aout[o];
    size_t p = (size_t)b * A_TOTAL + (size_t)a;
    float* op = out5 + p * 5;
    op[0] = pq.x; op[1] = pq.y; op[2] = pq.z; op[3] = pq.w; op[4] = sc;
    keepo[p] = 1.0f;
  }
}

extern "C" void kernel_launch(void* const* d_in, const int* in_sizes, int n_in,
                              void* d_out, int out_size, void* d_ws, size_t ws_size,
                              hipStream_t stream) {
  const float *cls[5], *bbox[5];
  if (n_in >= 10 && in_sizes[1] == 4 * in_sizes[0]) {       // interleaved dict order
    for (int l = 0; l < 5; l++) { cls[l] = (const float*)d_in[2*l]; bbox[l] = (const float*)d_in[2*l+1]; }
  } else {                                                   // grouped order
    for (int l = 0; l < 5; l++) { cls[l] = (const float*)d_in[l]; bbox[l] = (const float*)d_in[5+l]; }
  }

  char* ws = (char*)d_ws;
  int* hp     = (int*)(ws + WS_HP);
  int* cnt    = (int*)(ws + WS_CNT);
  int* b0c    = (int*)(ws + WS_B0C);
  unsigned long long* cand = (unsigned long long*)(ws + WS_CAND);
  float4* iouA = (float4*)(ws + WS_IOUA);
  float4* pout = (float4*)(ws + WS_POUT);
  float*  sout = (float*)(ws + WS_SOUT);
  int*    aout = (int*)(ws + WS_AOUT);

  float* out5  = (float*)d_out;
  float* keepo = out5 + (size_t)NBATCH * A_TOTAL * 5;

  k_init<<<4096, 256, 0, stream>>>(cls[0], cls[1], cls[2], cls[3], cls[4],
                                   (float4*)d_out, (NBATCH * A_TOTAL * 6) / 4,
                                   cnt, hp);
  k_scan<<<NBATCH, 256, 0, stream>>>(hp, b0c);
  dim3 g64(64, NBATCH);
  k_compact<<<g64, 256, 0, stream>>>(cls[0], cls[1], cls[2], cls[3], cls[4],
                                     b0c, cnt, cand);
  dim3 gr(16, NBATCH);
  k_rank<<<gr, 64, 0, stream>>>(bbox[0], bbox[1], bbox[2], bbox[3], bbox[4],
                                cand, cnt, iouA, pout, sout, aout);
  k_nms<<<NBATCH, 1024, 0, stream>>>(iouA, pout, sout, aout, out5, keepo);
}

// Round 8
// 284.219 us; speedup vs baseline: 1.8046x; 1.8046x over previous
//
#include <hip/hip_runtime.h>
#include <cstdint>
#include <cstddef>

#define A_TOTAL 261888
#define NBATCH  16
#define KTOP    1000
#define CAP     2048
#define NMS_T   0.7f
#define F4_PER_IMG 65472          // 261888/4
#define F4_PER_BLK 1023           // 65472/64 blocks
#define STAGE_CAP 512             // per-block candidate staging (expected ~19)

// ---- ws layout (bytes) ----
#define WS_HP    0                 // 16*64*256*4 = 1,048,576  coarse hist partials
#define WS_CNT   1048576           // 16 ints (atomic accumulator -> zeroed in k_init)
#define WS_B0C   1048640           // 16 ints (threshold bin, written by k_scan)
#define WS_CAND  1048704           // 16*2048*8   = 262,144
#define WS_IOUA  1310848           // 16*1000*16  = 256,000
#define WS_POUT  1566848           // 256,000
#define WS_SOUT  1822848           // 64,000
#define WS_AOUT  1886848           // 64,000
#define WS_MASK  1950848           // 16*16*1000*8 = 2,048,000 ; end = 3,998,848

__constant__ float c_stride[5] = {4.f, 8.f, 16.f, 32.f, 64.f};
__constant__ float c_aw[5][3] = {
  {(float)(32.0 /0.707106769084930419921875),  32.f, (float)(32.0 /1.41421353816986083984375)},
  {(float)(64.0 /0.707106769084930419921875),  64.f, (float)(64.0 /1.41421353816986083984375)},
  {(float)(128.0/0.707106769084930419921875), 128.f, (float)(128.0/1.41421353816986083984375)},
  {(float)(256.0/0.707106769084930419921875), 256.f, (float)(256.0/1.41421353816986083984375)},
  {(float)(512.0/0.707106769084930419921875), 512.f, (float)(512.0/1.41421353816986083984375)}};
__constant__ float c_ah[5][3] = {
  {(float)(32.0 *0.707106769084930419921875),  32.f, (float)(32.0 *1.41421353816986083984375)},
  {(float)(64.0 *0.707106769084930419921875),  64.f, (float)(64.0 *1.41421353816986083984375)},
  {(float)(128.0*0.707106769084930419921875), 128.f, (float)(128.0*1.41421353816986083984375)},
  {(float)(256.0*0.707106769084930419921875), 256.f, (float)(256.0*1.41421353816986083984375)},
  {(float)(512.0*0.707106769084930419921875), 512.f, (float)(512.0*1.41421353816986083984375)}};

__device__ __forceinline__ void decompA(int a, int& l, int& i) {
  if (a < 245760) {
    if (a < 196608) { l = 0; i = a; } else { l = 1; i = a - 196608; }
  } else if (a < 258048) { l = 2; i = a - 245760; }
  else if (a < 261120)   { l = 3; i = a - 258048; }
  else                   { l = 4; i = a - 261120; }
}

__device__ __forceinline__ void decompE(int e, int& l, int& el) {
  if (e < 245760) {
    if (e < 196608) { l = 0; el = e; } else { l = 1; el = e - 196608; }
  } else if (e < 258048) { l = 2; el = e - 245760; }
  else if (e < 261120)   { l = 3; el = e - 258048; }
  else                   { l = 4; el = e - 261120; }
}

__device__ __forceinline__ int bin_of(float s) {
  int b = (int)(s * 16384.0f);
  return b > 16383 ? 16383 : (b < 0 ? 0 : b);
}

__device__ __forceinline__ float4 score4_at(const float* c0, const float* c1,
                                            const float* c2, const float* c3,
                                            const float* c4, int b, int f) {
  int l, off4;
  if (f < 49152) { l = 0; off4 = f; }
  else if (f < 61440) { l = 1; off4 = f - 49152; }
  else if (f < 64512) { l = 2; off4 = f - 61440; }
  else if (f < 65280) { l = 3; off4 = f - 64512; }
  else { l = 4; off4 = f - 65280; }
  int HW4x3 = 3 * (16384 >> (2 * l));
  const float4* p = (const float4*)((l == 0) ? c0 : (l == 1) ? c1 : (l == 2) ? c2
                                     : (l == 3) ? c3 : c4);
  float4 x = p[(size_t)b * HW4x3 + off4];
  float4 s;
  s.x = 1.0f / (1.0f + expf(-x.x));
  s.y = 1.0f / (1.0f + expf(-x.y));
  s.z = 1.0f / (1.0f + expf(-x.z));
  s.w = 1.0f / (1.0f + expf(-x.w));
  return s;
}

__device__ __forceinline__ void decode_box(const float* b0p, const float* b1p,
                                           const float* b2p, const float* b3p,
                                           const float* b4p, int b, int a,
                                           float& x1, float& y1, float& x2, float& y2,
                                           float& cx, float& cy, float& wb, float& hb) {
  int l, i; decompA(a, l, i);
  unsigned pix = (unsigned)i / 3u;
  int r = i - (int)pix * 3;
  int W = 256 >> l;
  int HW = 65536 >> (2 * l);
  int hh_i = (int)pix >> (8 - l);
  int ww_i = (int)pix & (W - 1);
  const float* bp = (l == 0) ? b0p : (l == 1) ? b1p : (l == 2) ? b2p : (l == 3) ? b3p : b4p;
  size_t base = (size_t)(b * 12 + r * 4) * HW + (size_t)pix;
  float d0 = bp[base];
  float d1 = bp[base + HW];
  float d2 = bp[base + 2 * (size_t)HW];
  float d3 = bp[base + 3 * (size_t)HW];
  float stride = c_stride[l];
  float cxa = ((float)ww_i + 0.5f) * stride;
  float cya = ((float)hh_i + 0.5f) * stride;
  float aw = c_aw[l][r], ah = c_ah[l][r];
  cx = cxa + d0 * aw;
  cy = cya + d1 * ah;
  wb = aw * expf(fminf(fmaxf(d2, -4.f), 4.f));
  hb = ah * expf(fminf(fmaxf(d3, -4.f), 4.f));
  x1 = cx - wb * 0.5f; x2 = cx + wb * 0.5f;
  y1 = cy - hb * 0.5f; y2 = cy + hb * 0.5f;
}

// ---------------- K1: zero output + cnt  AND  coarse histogram partials ----------------
__global__ __launch_bounds__(256) void k_init(const float* c0, const float* c1,
                                              const float* c2, const float* c3,
                                              const float* c4,
                                              float4* o, int n4, int* cnt, int* hp) {
  __shared__ int lh[256];
  int bx = blockIdx.x, tid = threadIdx.x;
  int gstride = gridDim.x * 256;
  float4 z = make_float4(0.f, 0.f, 0.f, 0.f);
  for (int i = bx * 256 + tid; i < n4; i += gstride) o[i] = z;
  if (bx == 0 && tid < NBATCH) cnt[tid] = 0;
  if (bx < 1024) {
    lh[tid] = 0;
    __syncthreads();
    int b = bx >> 6, blk = bx & 63;
    int f0 = blk * F4_PER_BLK;
    #pragma unroll
    for (int it = 0; it < 4; it++) {
      int f = f0 + it * 256 + tid;
      if (f < f0 + F4_PER_BLK) {
        float4 s = score4_at(c0, c1, c2, c3, c4, b, f);
        atomicAdd(&lh[bin_of(s.x) >> 6], 1);
        atomicAdd(&lh[bin_of(s.y) >> 6], 1);
        atomicAdd(&lh[bin_of(s.z) >> 6], 1);
        atomicAdd(&lh[bin_of(s.w) >> 6], 1);
      }
    }
    __syncthreads();
    hp[(size_t)(b * 64 + blk) * 256 + tid] = lh[tid];
  }
}

// ---------------- K2: one-shot threshold scan (16 blocks) ----------------
__global__ __launch_bounds__(256) void k_scan(const int* hp, int* b0c) {
  __shared__ int ch[256];
  int b = blockIdx.x, t = threadIdx.x;
  int s = 0;
  for (int k = 0; k < 64; k++) s += hp[(size_t)(b * 64 + k) * 256 + t];
  ch[t] = s;
  __syncthreads();
  if (t == 0) {
    int acc = 0, cs = 0;
    for (int cb = 255; cb >= 0; cb--) {
      if (acc + ch[cb] >= KTOP) { cs = cb; break; }
      acc += ch[cb];
    }
    b0c[b] = cs * 64;   // superset threshold; exact top-K recovered by ranking
  }
}

// ---------------- K3: compact superset candidates ----------------
__global__ __launch_bounds__(256) void k_compact(const float* c0, const float* c1,
                                                 const float* c2, const float* c3,
                                                 const float* c4, const int* b0c,
                                                 int* cnt, unsigned long long* cand) {
  __shared__ unsigned long long stage[STAGE_CAP];
  __shared__ int lc, gbase;
  int b = blockIdx.y, blk = blockIdx.x, tid = threadIdx.x;
  if (tid == 0) lc = 0;
  __syncthreads();
  int B0v = b0c[b];
  int f0 = blk * F4_PER_BLK;
  #pragma unroll
  for (int it = 0; it < 4; it++) {
    int f = f0 + it * 256 + tid;
    if (f < f0 + F4_PER_BLK) {
      float4 sc4 = score4_at(c0, c1, c2, c3, c4, b, f);
      float sv[4] = {sc4.x, sc4.y, sc4.z, sc4.w};
      #pragma unroll
      for (int j = 0; j < 4; j++) {
        if (bin_of(sv[j]) >= B0v) {
          int e = f * 4 + j;
          int l, el; decompE(e, l, el);
          int shift = 16 - 2 * l;
          int r = el >> shift;
          int pix = el & ((1 << shift) - 1);
          int a = (e - el) + pix * 3 + r;
          int pos = atomicAdd(&lc, 1);
          if (pos < STAGE_CAP) {
            unsigned key = ~__float_as_uint(sv[j]);
            stage[pos] = ((unsigned long long)key << 32) | (unsigned)a;
          }
        }
      }
    }
  }
  __syncthreads();
  if (tid == 0) {
    int c = lc; if (c > STAGE_CAP) c = STAGE_CAP;
    lc = c;
    gbase = atomicAdd(&cnt[b], c);
  }
  __syncthreads();
  int c = lc, g0 = gbase;
  for (int t = tid; t < c; t += 256) {
    int gp = g0 + t;
    if (gp < CAP) cand[(size_t)b * CAP + gp] = stage[t];
  }
}

// ---------------- K4: exact rank-by-count + decode (1 wave/block, 128 slots) ----------------
__global__ __launch_bounds__(64) void k_rank(const float* b0p, const float* b1p,
                                             const float* b2p, const float* b3p,
                                             const float* b4p,
                                             const unsigned long long* cand,
                                             const int* cnt,
                                             float4* iouA, float4* pout,
                                             float* sout, int* aout) {
  __shared__ unsigned long long sk[CAP];
  int b = blockIdx.y, g = blockIdx.x;
  int lane = threadIdx.x;
  int n = cnt[b]; if (n > CAP) n = CAP;
  for (int t = lane; t < CAP; t += 64)
    sk[t] = (t < n) ? cand[(size_t)b * CAP + t] : ~0ull;
  __syncthreads();
  int s0 = g * 128 + lane, s1 = s0 + 64;
  unsigned long long my0 = sk[s0], my1 = sk[s1];
  int r0 = 0, r1 = 0;
  #pragma unroll 4
  for (int j = 0; j < n; j++) {
    unsigned long long k = sk[j];
    r0 += (k < my0) ? 1 : 0;
    r1 += (k < my1) ? 1 : 0;
  }
  #pragma unroll
  for (int pass = 0; pass < 2; pass++) {
    int slot = pass == 0 ? s0 : s1;
    int r = pass == 0 ? r0 : r1;
    unsigned long long e = pass == 0 ? my0 : my1;
    if (slot < n && r < KTOP) {
      int a = (int)(unsigned)e;
      float sc = __uint_as_float(~(unsigned)(e >> 32));
      float x1, y1, x2, y2, cx, cy, wb, hb;
      decode_box(b0p, b1p, b2p, b3p, b4p, b, a, x1, y1, x2, y2, cx, cy, wb, hb);
      int o = b * KTOP + r;
      iouA[o] = make_float4(x1, y1, x2, y2);
      pout[o] = make_float4(cx, cy, wb, hb);
      sout[o] = sc;
      aout[o] = a;
    }
  }
}

// ---------------- K5: FULL symmetric IoU bit-matrix, transposed, conflict-free ----------------
// gmaskT[(b*16 + word)*KTOP + row] bit cr set iff col=word*64+cr != row, col<KTOP, IoU>thr
__global__ __launch_bounds__(1024) void k_iou(const float4* iouA,
                                              unsigned long long* gmaskT) {
  __shared__ float4 bx[KTOP];
  int b = blockIdx.y;
  int tid = threadIdx.x;
  if (tid < KTOP) bx[tid] = iouA[b * KTOP + tid];
  __syncthreads();
  int row = blockIdx.x * 64 + (tid >> 4);
  int cc = tid & 15;
  if (row >= KTOP) return;
  float4 rb = bx[row];
  float rar = (rb.z - rb.x) * (rb.w - rb.y);
  unsigned long long bits = 0;
  int cbase = cc * 64;
  #pragma unroll 4
  for (int c = 0; c < 64; c++) {
    int cr = (c + cc) & 63;           // rotate start per cc -> 2-way banks (free)
    int col = cbase + cr;
    if (col < KTOP && col != row) {
      float4 cb4 = bx[col];
      float iw = fminf(rb.z, cb4.z) - fmaxf(rb.x, cb4.x); iw = fmaxf(iw, 0.f);
      float ih = fminf(rb.w, cb4.w) - fmaxf(rb.y, cb4.y); ih = fmaxf(ih, 0.f);
      float inter = iw * ih;
      float car = (cb4.z - cb4.x) * (cb4.w - cb4.y);
      float iou = inter / (rar + car - inter + 1e-6f);
      if (iou > NMS_T) bits |= (1ull << cr);
    }
  }
  gmaskT[((size_t)b * 16 + cc) * KTOP + row] = bits;
}

// ---------------- K6: scalar-serial greedy (SALU chain, no ballots) + scatter ----------------
__global__ __launch_bounds__(1024) void k_greedy(const unsigned long long* gmaskT,
                                                 const float4* pout, const float* sout,
                                                 const int* aout,
                                                 float* out5, float* keepo) {
  __shared__ unsigned long long diag[1024];   // word c of chunk c's rows
  __shared__ unsigned long long rem[16];
  __shared__ unsigned long long keptv[16];
  int b = blockIdx.x;
  int tid = threadIdx.x;
  int wv = tid >> 6, lane = tid & 63;
  {
    int row = wv * 64 + lane;
    diag[tid] = (row < KTOP) ? gmaskT[((size_t)b * 16 + wv) * KTOP + row] : 0ull;
  }
  if (tid < 16) { rem[tid] = 0ull; keptv[tid] = 0ull; }
  __syncthreads();

  for (int c = 0; c < 16; c++) {
    // phase A: wave 0 resolves chunk c entirely in SGPRs (readlane + s_or chain)
    if (wv == 0) {
      unsigned long long dw = diag[c * 64 + lane];
      unsigned dlo = (unsigned)dw, dhi = (unsigned)(dw >> 32);
      unsigned long long r0 = rem[c];
      if (c == 15) r0 |= ~((1ull << 40) - 1);   // rows >= KTOP pre-suppressed
      unsigned slo = __builtin_amdgcn_readfirstlane((unsigned)r0);
      unsigned shi = __builtin_amdgcn_readfirstlane((unsigned)(r0 >> 32));
      unsigned klo = 0u, khi = 0u;
      #pragma unroll
      for (int i = 0; i < 32; i++) {
        unsigned t = (~slo >> i) & 1u;
        unsigned m = 0u - t;
        klo |= t << i;
        slo |= __builtin_amdgcn_readlane(dlo, i) & m;
        shi |= __builtin_amdgcn_readlane(dhi, i) & m;
      }
      #pragma unroll
      for (int i = 0; i < 32; i++) {
        unsigned t = (~shi >> i) & 1u;
        unsigned m = 0u - t;
        khi |= t << i;
        slo |= __builtin_amdgcn_readlane(dlo, 32 + i) & m;
        shi |= __builtin_amdgcn_readlane(dhi, 32 + i) & m;
      }
      if (lane == 0) keptv[c] = ((unsigned long long)khi << 32) | klo;
    }
    __syncthreads();
    // phase B: wave wv ORs kept rows' word-wv into rem[wv]
    if (c < 15) {
      unsigned long long km = keptv[c];
      unsigned long long v = 0ull;
      if ((km >> lane) & 1ull) {
        int row = c * 64 + lane;
        v = gmaskT[((size_t)b * 16 + wv) * KTOP + row];
      }
      #pragma unroll
      for (int o = 32; o > 0; o >>= 1) v |= __shfl_xor(v, o, 64);
      if (lane == 0) rem[wv] |= v;
      __syncthreads();
    }
  }

  // scatter write
  if (tid < KTOP && ((keptv[tid >> 6] >> (tid & 63)) & 1ull)) {
    int o = b * KTOP + tid;
    float4 pq = pout[o];
    float sc = sout[o];
    int a = aout[o];
    size_t p = (size_t)b * A_TOTAL + (size_t)a;
    float* op = out5 + p * 5;
    op[0] = pq.x; op[1] = pq.y; op[2] = pq.z; op[3] = pq.w; op[4] = sc;
    keepo[p] = 1.0f;
  }
}

extern "C" void kernel_launch(void* const* d_in, const int* in_sizes, int n_in,
                              void* d_out, int out_size, void* d_ws, size_t ws_size,
                              hipStream_t stream) {
  const float *cls[5], *bbox[5];
  if (n_in >= 10 && in_sizes[1] == 4 * in_sizes[0]) {       // interleaved dict order
    for (int l = 0; l < 5; l++) { cls[l] = (const float*)d_in[2*l]; bbox[l] = (const float*)d_in[2*l+1]; }
  } else {                                                   // grouped order
    for (int l = 0; l < 5; l++) { cls[l] = (const float*)d_in[l]; bbox[l] = (const float*)d_in[5+l]; }
  }

  char* ws = (char*)d_ws;
  int* hp     = (int*)(ws + WS_HP);
  int* cnt    = (int*)(ws + WS_CNT);
  int* b0c    = (int*)(ws + WS_B0C);
  unsigned long long* cand = (unsigned long long*)(ws + WS_CAND);
  float4* iouA = (float4*)(ws + WS_IOUA);
  float4* pout = (float4*)(ws + WS_POUT);
  float*  sout = (float*)(ws + WS_SOUT);
  int*    aout = (int*)(ws + WS_AOUT);
  unsigned long long* gmaskT = (unsigned long long*)(ws + WS_MASK);

  float* out5  = (float*)d_out;
  float* keepo = out5 + (size_t)NBATCH * A_TOTAL * 5;

  k_init<<<4096, 256, 0, stream>>>(cls[0], cls[1], cls[2], cls[3], cls[4],
                                   (float4*)d_out, (NBATCH * A_TOTAL * 6) / 4,
                                   cnt, hp);
  k_scan<<<NBATCH, 256, 0, stream>>>(hp, b0c);
  dim3 g64(64, NBATCH);
  k_compact<<<g64, 256, 0, stream>>>(cls[0], cls[1], cls[2], cls[3], cls[4],
                                     b0c, cnt, cand);
  dim3 gr(16, NBATCH);
  k_rank<<<gr, 64, 0, stream>>>(bbox[0], bbox[1], bbox[2], bbox[3], bbox[4],
                                cand, cnt, iouA, pout, sout, aout);
  dim3 gi(16, NBATCH);
  k_iou<<<gi, 1024, 0, stream>>>(iouA, gmaskT);
  k_greedy<<<NBATCH, 1024, 0, stream>>>(gmaskT, pout, sout, aout, out5, keepo);
}